// Round 9
// baseline (658.250 us; speedup 1.0000x reference)
//
#include <hip/hip_runtime.h>

// PatientMeanEncoder: causal nonzero-mean pool over concat(timesteps, MLP(dem)).
// N=64, L=2048, C_IN=256, DEM=10, hidden 40 -> 20, C_OUT = 276.
//
// R14: MEASUREMENT ROUND. Kernels are byte-identical to R13. The launcher
// runs pme_scan SIX times (idempotent: reads ts/part, writes the same out).
// Delta vs R13's dur = 5 x (k2 + launch gap) -> pins k2's duration, which
// has been invisible for six rounds (both kernels sit below the ~90 us
// fill-dispatch top-5 cutoff). Decision rule (pre-committed):
//   k2 >= 60 us -> attack k2's store path (tail placement / NT / granule
//                  alignment) next round;
//   k2 <= 35 us -> kernels are minor vs harness overhead; near practical
//                  roofline, confirm and stop;
//   else        -> duplicate k1 next round to complete the split.
//
// dem channels are constant along l, so causal nonzero-mean == the MLP
// output itself (v>0: (l+1)v/(l+1)=v; v==0: 0/max(0,1)=0).

#define NB 64
#define LL 2048
#define CIN 256
#define COUT 276
#define DEMD 10
#define H1 40
#define H2 20

#define SEGS 64              // segments per patient
#define SROWS (LL / SEGS)    // 32 rows per segment
#define UB 8                 // rows per prefetch batch (8 KB in flight / wave)
#define NBATCH (SROWS / UB)  // 4
#define NUNITS (NB * SEGS)   // 4096 waves
#define NBLK (NUNITS / 4)    // 1024 blocks

// ------ kernel 1: partials + group-local inclusive prefix (4 segs/block) ------
__global__ __launch_bounds__(256) void pme_part(
    const float* __restrict__ ts,   // (N, L, 256)
    float* __restrict__ part)       // (N, SEGS, 256) x {sum, cnt}, group-inclusive
{
    __shared__ float4 P0[4][64];    // own partials, pair 0 (4 KB)
    __shared__ float4 P1[4][64];    // own partials, pair 1 (4 KB)

    const int tid  = threadIdx.x;
    const int w    = tid >> 6;
    const int lane = tid & 63;

    const int unit = blockIdx.x * 4 + w;    // 4 consecutive segs of one n
    const int seg  = unit & (SEGS - 1);
    const int n    = unit >> 6;

    const float4* tp = (const float4*)(ts + ((size_t)n * LL + seg * SROWS) * CIN) + lane;

    float4 sum = make_float4(0.f, 0.f, 0.f, 0.f);
    float4 ctv = make_float4(0.f, 0.f, 0.f, 0.f);

    float4 v[2][UB];
#pragma unroll
    for (int u = 0; u < UB; ++u)
        v[0][u] = tp[(size_t)u * (CIN / 4)];

    for (int bb = 0; bb < NBATCH; ++bb) {
        const int cur = bb & 1;
        if (bb + 1 < NBATCH) {
#pragma unroll
            for (int u = 0; u < UB; ++u)
                v[cur ^ 1][u] = tp[(size_t)((bb + 1) * UB + u) * (CIN / 4)];
        }
#pragma unroll
        for (int u = 0; u < UB; ++u) {
            float4 x = v[cur][u];
            sum.x += x.x; ctv.x += (x.x != 0.f) ? 1.f : 0.f;
            sum.y += x.y; ctv.y += (x.y != 0.f) ? 1.f : 0.f;
            sum.z += x.z; ctv.z += (x.z != 0.f) ? 1.f : 0.f;
            sum.w += x.w; ctv.w += (x.w != 0.f) ? 1.f : 0.f;
        }
    }

    P0[w][lane] = make_float4(sum.x, ctv.x, sum.y, ctv.y);
    P1[w][lane] = make_float4(sum.z, ctv.z, sum.w, ctv.w);
    __syncthreads();

    // wave w accumulates waves 0..w  -> group-local inclusive prefix
    float4 A = make_float4(0.f, 0.f, 0.f, 0.f);
    float4 C = make_float4(0.f, 0.f, 0.f, 0.f);
    for (int e = 0; e <= w; ++e) {          // wave-uniform trip count
        float4 a = P0[e][lane];
        float4 c = P1[e][lane];
        A.x += a.x; A.y += a.y; A.z += a.z; A.w += a.w;
        C.x += c.x; C.y += c.y; C.z += c.z; C.w += c.w;
    }
    float4* pp = (float4*)part + ((size_t)n * SEGS + seg) * 128 + lane * 2;
    pp[0] = A;
    pp[1] = C;
}

// ------- kernel 2: short prefix + scan + fused dem write ------------------
__global__ __launch_bounds__(256) void pme_scan(
    const float* __restrict__ ts,   // (N, L, 256)
    const float* __restrict__ part, // (N, SEGS, 256) group-inclusive prefixes
    const float* __restrict__ dem,  // (N, 10)
    const float* __restrict__ W1, const float* __restrict__ b1,
    const float* __restrict__ W2, const float* __restrict__ b2,
    float* __restrict__ out)        // (N, L, 276)
{
    __shared__ float4 QS[4][64];    // strided group-total sums, pair 0 (4 KB)
    __shared__ float4 QC[4][64];    // strided group-total sums, pair 1 (4 KB)

    const int tid  = threadIdx.x;
    const int w    = tid >> 6;
    const int lane = tid & 63;

    const int b       = blockIdx.x;
    const int n       = b >> 4;          // 16 blocks per patient
    const int grp     = b & 15;
    const int segbase = grp * 4;
    const int seg     = segbase + w;

    const float4* tp = (const float4*)(ts + ((size_t)n * LL + seg * SROWS) * CIN) + lane;

    // issue the first ts prefetch batch early: overlaps prefix + MLP
    float4 v[2][UB];
#pragma unroll
    for (int u = 0; u < UB; ++u)
        v[0][u] = tp[(size_t)u * (CIN / 4)];

    // ---- exclusive prefix: <=15 group-total slots, 4-way strided ----
    const float4* base = (const float4*)part + (size_t)n * SEGS * 128 + lane * 2;

    float4 A = make_float4(0.f, 0.f, 0.f, 0.f);
    float4 C = make_float4(0.f, 0.f, 0.f, 0.f);
    for (int g = w; g < grp; g += 4) {       // wave-uniform trip count (<=4)
        float4 a = base[(size_t)(4 * g + 3) * 128];
        float4 c = base[(size_t)(4 * g + 3) * 128 + 1];
        A.x += a.x; A.y += a.y; A.z += a.z; A.w += a.w;
        C.x += c.x; C.y += c.y; C.z += c.z; C.w += c.w;
    }
    QS[w][lane] = A;
    QC[w][lane] = C;
    __syncthreads();

    A = make_float4(0.f, 0.f, 0.f, 0.f);
    C = make_float4(0.f, 0.f, 0.f, 0.f);
#pragma unroll
    for (int s = 0; s < 4; ++s) {
        float4 a = QS[s][lane];
        float4 c = QC[s][lane];
        A.x += a.x; A.y += a.y; A.z += a.z; A.w += a.w;
        C.x += c.x; C.y += c.y; C.z += c.z; C.w += c.w;
    }
    if (w > 0) {                             // own-group local inclusive prefix
        float4 a = base[(size_t)(segbase + w - 1) * 128];
        float4 c = base[(size_t)(segbase + w - 1) * 128 + 1];
        A.x += a.x; A.y += a.y; A.z += a.z; A.w += a.w;
        C.x += c.x; C.y += c.y; C.z += c.z; C.w += c.w;
    }
    float4 acc = make_float4(A.x, A.z, C.x, C.z);
    float4 cnt = make_float4(A.y, A.w, C.y, C.w);

    // ---- dem MLP: lane computes the chunk (lane%5) it will store ----
    const int tr = lane / 5;        // tail row within group (0..12)
    const int tj = lane - tr * 5;   // tail chunk (0..4)
    float4 e4q;
    {
        const float* dn = dem + n * DEMD;
        float d[DEMD];
#pragma unroll
        for (int i = 0; i < DEMD; ++i)
            d[i] = dn[i];
        float e0 = b2[tj * 4 + 0], e1 = b2[tj * 4 + 1], e2 = b2[tj * 4 + 2], e3 = b2[tj * 4 + 3];
#pragma unroll
        for (int k = 0; k < H1; ++k) {
            float hk = b1[k];
#pragma unroll
            for (int i = 0; i < DEMD; ++i)
                hk += d[i] * W1[i * H1 + k];
            hk = fmaxf(hk, 0.f);
            e0 += hk * W2[k * H2 + tj * 4 + 0];
            e1 += hk * W2[k * H2 + tj * 4 + 1];
            e2 += hk * W2[k * H2 + tj * 4 + 2];
            e3 += hk * W2[k * H2 + tj * 4 + 3];
        }
        e4q = make_float4(fmaxf(e0, 0.f), fmaxf(e1, 0.f), fmaxf(e2, 0.f), fmaxf(e3, 0.f));
    }

    // ---- stream 32 rows (MALL-resident), scan, regular stores ----
    float* oprow = out + ((size_t)n * LL + seg * SROWS) * COUT;

    for (int bb = 0; bb < NBATCH; ++bb) {
        const int cur = bb & 1;
        if (bb + 1 < NBATCH) {
#pragma unroll
            for (int u = 0; u < UB; ++u)
                v[cur ^ 1][u] = tp[(size_t)((bb + 1) * UB + u) * (CIN / 4)];
        }
#pragma unroll
        for (int u = 0; u < UB; ++u) {
            float4 x = v[cur][u];
            float4 r;
            acc.x += x.x; cnt.x += (x.x != 0.f) ? 1.f : 0.f;
            acc.y += x.y; cnt.y += (x.y != 0.f) ? 1.f : 0.f;
            acc.z += x.z; cnt.z += (x.z != 0.f) ? 1.f : 0.f;
            acc.w += x.w; cnt.w += (x.w != 0.f) ? 1.f : 0.f;
            r.x = fmaxf(acc.x * __builtin_amdgcn_rcpf(fmaxf(cnt.x, 1.f)), 0.f);
            r.y = fmaxf(acc.y * __builtin_amdgcn_rcpf(fmaxf(cnt.y, 1.f)), 0.f);
            r.z = fmaxf(acc.z * __builtin_amdgcn_rcpf(fmaxf(cnt.z, 1.f)), 0.f);
            r.w = fmaxf(acc.w * __builtin_amdgcn_rcpf(fmaxf(cnt.w, 1.f)), 0.f);
            *(float4*)(oprow + (size_t)(bb * UB + u) * COUT + lane * 4) = r;
        }
    }

    // ---- dem tails: 3 scatter stores cover all 32 rows (12+12+8) ----
    float* tailbase = oprow + CIN;
    if (lane < 60) {
        *(float4*)(tailbase + (size_t)(0  + tr) * COUT + tj * 4) = e4q;
        *(float4*)(tailbase + (size_t)(12 + tr) * COUT + tj * 4) = e4q;
    }
    if (lane < 40)
        *(float4*)(tailbase + (size_t)(24 + tr) * COUT + tj * 4) = e4q;
}

extern "C" void kernel_launch(void* const* d_in, const int* in_sizes, int n_in,
                              void* d_out, int out_size, void* d_ws, size_t ws_size,
                              hipStream_t stream) {
    const float* ts  = (const float*)d_in[0];
    const float* dem = (const float*)d_in[1];
    const float* W1  = (const float*)d_in[2];
    const float* b1  = (const float*)d_in[3];
    const float* W2  = (const float*)d_in[4];
    const float* b2  = (const float*)d_in[5];
    float* out  = (float*)d_out;
    float* part = (float*)d_ws;   // 64*64*256*2 floats = 8.39 MB

    pme_part<<<NBLK, 256, 0, stream>>>(ts, part);
    // MEASUREMENT: pme_scan is idempotent; 6 launches give
    // dur_R14 - dur_R13 = 5 x (k2 + gap) -> pins k2's duration.
    for (int rep = 0; rep < 6; ++rep)
        pme_scan<<<NBLK, 256, 0, stream>>>(ts, part, dem, W1, b1, W2, b2, out);
}

// Round 10
// 300.549 us; speedup vs baseline: 2.1902x; 2.1902x over previous
//
#include <hip/hip_runtime.h>

// PatientMeanEncoder: causal nonzero-mean pool over concat(timesteps, MLP(dem)).
// N=64, L=2048, C_IN=256, DEM=10, hidden 40 -> 20, C_OUT = 276.
//
// R15: store-path fix, single change vs R13. R14's replication probe pinned
// k2 ~= 68-70 us (5x(k2+gap) = 357 us). Theory: write amplification from
// time-split granules. Row stride 1104 B = 4.31 x 256-B granules; the granule
// [1024,1280) of row r gets row r+1's first 176 B mid-loop and row r's 80 B
// dem-tail at KERNEL END (R9 batched the tails) -> L2 (4 MB/XCD, ~18 MB
// written between touches) evicts partially-dirty -> 2 partial writebacks
// per row (~+35-70 MB, matching R2's measured 234 vs 145 MB ideal).
// R0-R8: in-loop tails but NT stores (no merging). R9-R13: mergeable stores
// but end-batched tails. This round: BOTH regular stores AND in-loop tails --
// every granule's writers land within a few hundred cycles.
// Keep: k1 group-inclusive prefixes, k2 short prefix (<=4+1 serial), early
// first-batch prefetch, 16 waves/CU.
//
// dem channels are constant along l, so causal nonzero-mean == the MLP
// output itself (v>0: (l+1)v/(l+1)=v; v==0: 0/max(0,1)=0).

#define NB 64
#define LL 2048
#define CIN 256
#define COUT 276
#define DEMD 10
#define H1 40
#define H2 20

#define SEGS 64              // segments per patient
#define SROWS (LL / SEGS)    // 32 rows per segment
#define UB 8                 // rows per prefetch batch (8 KB in flight / wave)
#define NBATCH (SROWS / UB)  // 4
#define NUNITS (NB * SEGS)   // 4096 waves
#define NBLK (NUNITS / 4)    // 1024 blocks

// ------ kernel 1: partials + group-local inclusive prefix (4 segs/block) ------
__global__ __launch_bounds__(256) void pme_part(
    const float* __restrict__ ts,   // (N, L, 256)
    float* __restrict__ part)       // (N, SEGS, 256) x {sum, cnt}, group-inclusive
{
    __shared__ float4 P0[4][64];    // own partials, pair 0 (4 KB)
    __shared__ float4 P1[4][64];    // own partials, pair 1 (4 KB)

    const int tid  = threadIdx.x;
    const int w    = tid >> 6;
    const int lane = tid & 63;

    const int unit = blockIdx.x * 4 + w;    // 4 consecutive segs of one n
    const int seg  = unit & (SEGS - 1);
    const int n    = unit >> 6;

    const float4* tp = (const float4*)(ts + ((size_t)n * LL + seg * SROWS) * CIN) + lane;

    float4 sum = make_float4(0.f, 0.f, 0.f, 0.f);
    float4 ctv = make_float4(0.f, 0.f, 0.f, 0.f);

    float4 v[2][UB];
#pragma unroll
    for (int u = 0; u < UB; ++u)
        v[0][u] = tp[(size_t)u * (CIN / 4)];

    for (int bb = 0; bb < NBATCH; ++bb) {
        const int cur = bb & 1;
        if (bb + 1 < NBATCH) {
#pragma unroll
            for (int u = 0; u < UB; ++u)
                v[cur ^ 1][u] = tp[(size_t)((bb + 1) * UB + u) * (CIN / 4)];
        }
#pragma unroll
        for (int u = 0; u < UB; ++u) {
            float4 x = v[cur][u];
            sum.x += x.x; ctv.x += (x.x != 0.f) ? 1.f : 0.f;
            sum.y += x.y; ctv.y += (x.y != 0.f) ? 1.f : 0.f;
            sum.z += x.z; ctv.z += (x.z != 0.f) ? 1.f : 0.f;
            sum.w += x.w; ctv.w += (x.w != 0.f) ? 1.f : 0.f;
        }
    }

    P0[w][lane] = make_float4(sum.x, ctv.x, sum.y, ctv.y);
    P1[w][lane] = make_float4(sum.z, ctv.z, sum.w, ctv.w);
    __syncthreads();

    // wave w accumulates waves 0..w  -> group-local inclusive prefix
    float4 A = make_float4(0.f, 0.f, 0.f, 0.f);
    float4 C = make_float4(0.f, 0.f, 0.f, 0.f);
    for (int e = 0; e <= w; ++e) {          // wave-uniform trip count
        float4 a = P0[e][lane];
        float4 c = P1[e][lane];
        A.x += a.x; A.y += a.y; A.z += a.z; A.w += a.w;
        C.x += c.x; C.y += c.y; C.z += c.z; C.w += c.w;
    }
    float4* pp = (float4*)part + ((size_t)n * SEGS + seg) * 128 + lane * 2;
    pp[0] = A;
    pp[1] = C;
}

// ------- kernel 2: short prefix + scan + fused dem write ------------------
__global__ __launch_bounds__(256) void pme_scan(
    const float* __restrict__ ts,   // (N, L, 256)
    const float* __restrict__ part, // (N, SEGS, 256) group-inclusive prefixes
    const float* __restrict__ dem,  // (N, 10)
    const float* __restrict__ W1, const float* __restrict__ b1,
    const float* __restrict__ W2, const float* __restrict__ b2,
    float* __restrict__ out)        // (N, L, 276)
{
    __shared__ float4 QS[4][64];    // strided group-total sums, pair 0 (4 KB)
    __shared__ float4 QC[4][64];    // strided group-total sums, pair 1 (4 KB)

    const int tid  = threadIdx.x;
    const int w    = tid >> 6;
    const int lane = tid & 63;

    const int b       = blockIdx.x;
    const int n       = b >> 4;          // 16 blocks per patient
    const int grp     = b & 15;
    const int segbase = grp * 4;
    const int seg     = segbase + w;

    const float4* tp = (const float4*)(ts + ((size_t)n * LL + seg * SROWS) * CIN) + lane;

    // issue the first ts prefetch batch early: overlaps prefix + MLP
    float4 v[2][UB];
#pragma unroll
    for (int u = 0; u < UB; ++u)
        v[0][u] = tp[(size_t)u * (CIN / 4)];

    // ---- exclusive prefix: <=15 group-total slots, 4-way strided ----
    const float4* base = (const float4*)part + (size_t)n * SEGS * 128 + lane * 2;

    float4 A = make_float4(0.f, 0.f, 0.f, 0.f);
    float4 C = make_float4(0.f, 0.f, 0.f, 0.f);
    for (int g = w; g < grp; g += 4) {       // wave-uniform trip count (<=4)
        float4 a = base[(size_t)(4 * g + 3) * 128];
        float4 c = base[(size_t)(4 * g + 3) * 128 + 1];
        A.x += a.x; A.y += a.y; A.z += a.z; A.w += a.w;
        C.x += c.x; C.y += c.y; C.z += c.z; C.w += c.w;
    }
    QS[w][lane] = A;
    QC[w][lane] = C;
    __syncthreads();

    A = make_float4(0.f, 0.f, 0.f, 0.f);
    C = make_float4(0.f, 0.f, 0.f, 0.f);
#pragma unroll
    for (int s = 0; s < 4; ++s) {
        float4 a = QS[s][lane];
        float4 c = QC[s][lane];
        A.x += a.x; A.y += a.y; A.z += a.z; A.w += a.w;
        C.x += c.x; C.y += c.y; C.z += c.z; C.w += c.w;
    }
    if (w > 0) {                             // own-group local inclusive prefix
        float4 a = base[(size_t)(segbase + w - 1) * 128];
        float4 c = base[(size_t)(segbase + w - 1) * 128 + 1];
        A.x += a.x; A.y += a.y; A.z += a.z; A.w += a.w;
        C.x += c.x; C.y += c.y; C.z += c.z; C.w += c.w;
    }
    float4 acc = make_float4(A.x, A.z, C.x, C.z);
    float4 cnt = make_float4(A.y, A.w, C.y, C.w);

    // ---- dem MLP: lanes 0..4 hold tail chunks 0..4 (tj = lane%5) ----
    const int tr = lane / 5;
    const int tj = lane - tr * 5;
    float4 e4q;
    {
        const float* dn = dem + n * DEMD;
        float d[DEMD];
#pragma unroll
        for (int i = 0; i < DEMD; ++i)
            d[i] = dn[i];
        float e0 = b2[tj * 4 + 0], e1 = b2[tj * 4 + 1], e2 = b2[tj * 4 + 2], e3 = b2[tj * 4 + 3];
#pragma unroll
        for (int k = 0; k < H1; ++k) {
            float hk = b1[k];
#pragma unroll
            for (int i = 0; i < DEMD; ++i)
                hk += d[i] * W1[i * H1 + k];
            hk = fmaxf(hk, 0.f);
            e0 += hk * W2[k * H2 + tj * 4 + 0];
            e1 += hk * W2[k * H2 + tj * 4 + 1];
            e2 += hk * W2[k * H2 + tj * 4 + 2];
            e3 += hk * W2[k * H2 + tj * 4 + 3];
        }
        e4q = make_float4(fmaxf(e0, 0.f), fmaxf(e1, 0.f), fmaxf(e2, 0.f), fmaxf(e3, 0.f));
    }

    // ---- stream 32 rows (MALL-resident), scan, regular stores ----
    // Tail stored IN-LOOP right after each row's main store: all writers of
    // any 256-B granule land within a few hundred cycles -> full-line L2
    // writebacks, no partial-granule amplification.
    float* oprow = out + ((size_t)n * LL + seg * SROWS) * COUT;

    for (int bb = 0; bb < NBATCH; ++bb) {
        const int cur = bb & 1;
        if (bb + 1 < NBATCH) {
#pragma unroll
            for (int u = 0; u < UB; ++u)
                v[cur ^ 1][u] = tp[(size_t)((bb + 1) * UB + u) * (CIN / 4)];
        }
#pragma unroll
        for (int u = 0; u < UB; ++u) {
            float4 x = v[cur][u];
            float4 r;
            acc.x += x.x; cnt.x += (x.x != 0.f) ? 1.f : 0.f;
            acc.y += x.y; cnt.y += (x.y != 0.f) ? 1.f : 0.f;
            acc.z += x.z; cnt.z += (x.z != 0.f) ? 1.f : 0.f;
            acc.w += x.w; cnt.w += (x.w != 0.f) ? 1.f : 0.f;
            r.x = fmaxf(acc.x * __builtin_amdgcn_rcpf(fmaxf(cnt.x, 1.f)), 0.f);
            r.y = fmaxf(acc.y * __builtin_amdgcn_rcpf(fmaxf(cnt.y, 1.f)), 0.f);
            r.z = fmaxf(acc.z * __builtin_amdgcn_rcpf(fmaxf(cnt.z, 1.f)), 0.f);
            r.w = fmaxf(acc.w * __builtin_amdgcn_rcpf(fmaxf(cnt.w, 1.f)), 0.f);
            float* rowp = oprow + (size_t)(bb * UB + u) * COUT;
            *(float4*)(rowp + lane * 4) = r;              // channels 0..255
            if (lane < 5)
                *(float4*)(rowp + CIN + lane * 4) = e4q;  // channels 256..275
        }
    }
}

extern "C" void kernel_launch(void* const* d_in, const int* in_sizes, int n_in,
                              void* d_out, int out_size, void* d_ws, size_t ws_size,
                              hipStream_t stream) {
    const float* ts  = (const float*)d_in[0];
    const float* dem = (const float*)d_in[1];
    const float* W1  = (const float*)d_in[2];
    const float* b1  = (const float*)d_in[3];
    const float* W2  = (const float*)d_in[4];
    const float* b2  = (const float*)d_in[5];
    float* out  = (float*)d_out;
    float* part = (float*)d_ws;   // 64*64*256*2 floats = 8.39 MB

    pme_part<<<NBLK, 256, 0, stream>>>(ts, part);
    pme_scan<<<NBLK, 256, 0, stream>>>(ts, part, dem, W1, b1, W2, b2, out);
}